// Round 1
// baseline (4474.424 us; speedup 1.0000x reference)
//
#include <hip/hip_runtime.h>
#include <cstdint>
#include <cstddef>

// ---------------------------------------------------------------------------
// MixtureStochasticConvBlock — fp32 reference-faithful implementation.
// B=256, C_IN=256, C_V=128, C_OUT=256, H=W=16, K=4, TAU=1.
// Output layout (floats, concatenated):
//   out       [256,256,16,16]  @ 0
//   z         [256,128,16,16]  @ 16777216
//   logprob_p [256,128,16,16,4]@ 25165824
//   logprob_q [256,128,16,16]  @ 58720256
//   kl_total  scalar           @ 67108864
//   q_mu      [256,128,16,16]  @ 67108865
//   q_lv      [256,128,16,16]  @ 75497473
//   y         [256,4]          @ 83886081
//   cross_ent scalar           @ 83887105
// ---------------------------------------------------------------------------

#define LOG2PI_HALF 0.91893853320467274f

static constexpr size_t OFF_OUT = 0;
static constexpr size_t OFF_Z   = 16777216;
static constexpr size_t OFF_LP  = 25165824;
static constexpr size_t OFF_LQ  = 58720256;
static constexpr size_t OFF_KL  = 67108864;
static constexpr size_t OFF_QMU = 67108865;
static constexpr size_t OFF_QLV = 75497473;
static constexpr size_t OFF_Y   = 83886081;
static constexpr size_t OFF_CE  = 83887105;

__global__ void zero_scalars(float* __restrict__ out) {
    if (threadIdx.x == 0) {
        out[OFF_KL] = 0.f;
        out[OFF_CE] = 0.f;
    }
}

// Transform OIHW conv weights -> [kpos][ci][co] so conv staging is coalesced.
__global__ void wtrans_kernel(const float* __restrict__ w, float* __restrict__ wt,
                              int CIN, int COUT) {
    int idx = blockIdx.x * 256 + threadIdx.x;
    int total = CIN * COUT * 9;
    if (idx >= total) return;
    int co = idx % COUT;
    int t  = idx / COUT;
    int ci = t % CIN;
    int kpos = t / CIN;
    wt[idx] = w[((size_t)co * CIN + ci) * 9 + kpos];
}

// 3x3 SAME conv, NCHW, 16x16 spatial. Block: 1 batch x 64 couts x 256 pixels.
// Thread tile: 2 quads of 4 horizontally-adjacent pixels x 8 couts.
template <int CIN, int COUT, bool RELU, bool FUSE_GB>
__global__ __launch_bounds__(256, 2)
void conv3x3_kernel(const float* __restrict__ in, const float* __restrict__ wt,
                    const float* __restrict__ bias,
                    const float* __restrict__ gamma, const float* __restrict__ beta,
                    float* __restrict__ out) {
    constexpr int CK = 16;                 // cin chunk
    __shared__ __align__(16) float s_in[CK * 18 * 20];  // rows padded 18->20 for 16B align
    __shared__ __align__(16) float s_w[9 * CK * 64];    // [kpos][ci][co]

    const int tiles = COUT / 64;
    const int b  = blockIdx.x / tiles;
    const int tc = blockIdx.x % tiles;
    const int tid = threadIdx.x;
    const int s   = tid & 31;        // pixel-slot
    const int y   = s >> 2;          // 0..7  (rows y and y+8)
    const int x0  = (s & 3) * 4;     // 0,4,8,12
    const int co0 = (tid >> 5) * 8;  // 8-cout group within 64

    float acc[2][8][4];
#pragma unroll
    for (int q = 0; q < 2; q++)
#pragma unroll
        for (int j = 0; j < 8; j++)
#pragma unroll
            for (int p = 0; p < 4; p++) acc[q][j][p] = 0.f;

    const float* inb = in + (size_t)b * CIN * 256;

    for (int cc = 0; cc < CIN; cc += CK) {
        __syncthreads();
        // stage input chunk (zero-padded halo); apply gamma*x+beta if fused
        for (int idx = tid; idx < CK * 324; idx += 256) {
            int ci = idx / 324;
            int r  = idx - ci * 324;
            int yy = r / 18;
            int xx = r - yy * 18;
            float v = 0.f;
            int iy = yy - 1, ix = xx - 1;
            if ((unsigned)iy < 16u && (unsigned)ix < 16u) {
                v = inb[(cc + ci) * 256 + iy * 16 + ix];
                if (FUSE_GB)
                    v = fmaf(gamma[b * CIN + cc + ci], v, beta[b * CIN + cc + ci]);
            }
            s_in[ci * 360 + yy * 20 + xx] = v;
        }
        // stage weights: contiguous in both global (wt) and LDS
        for (int idx = tid; idx < 9 * CK * 64; idx += 256) {
            int kpos = idx >> 10;            // / (CK*64)
            int rem  = idx & 1023;
            int ci   = rem >> 6;
            int co   = rem & 63;
            s_w[idx] = wt[((size_t)kpos * CIN + cc + ci) * COUT + tc * 64 + co];
        }
        __syncthreads();

        for (int ci = 0; ci < CK; ++ci) {
            const float* si = &s_in[ci * 360];
            float iv[6][6];
#pragma unroll
            for (int q = 0; q < 2; q++)
#pragma unroll
                for (int r = 0; r < 3; r++) {
                    const float* rp = si + (y + 8 * q + r) * 20 + x0;
                    float4 v4 = *(const float4*)rp;
                    float2 v2 = *(const float2*)(rp + 4);
                    iv[q * 3 + r][0] = v4.x; iv[q * 3 + r][1] = v4.y;
                    iv[q * 3 + r][2] = v4.z; iv[q * 3 + r][3] = v4.w;
                    iv[q * 3 + r][4] = v2.x; iv[q * 3 + r][5] = v2.y;
                }
#pragma unroll
            for (int kh = 0; kh < 3; kh++)
#pragma unroll
                for (int kw = 0; kw < 3; kw++) {
                    const float* swp = &s_w[((kh * 3 + kw) * CK + ci) * 64 + co0];
                    float wv[8];
#pragma unroll
                    for (int j = 0; j < 8; j++) wv[j] = swp[j];
#pragma unroll
                    for (int q = 0; q < 2; q++)
#pragma unroll
                        for (int p = 0; p < 4; p++) {
                            float a = iv[q * 3 + kh][kw + p];
#pragma unroll
                            for (int j = 0; j < 8; j++)
                                acc[q][j][p] = fmaf(a, wv[j], acc[q][j][p]);
                        }
                }
        }
    }

    // epilogue: +bias (, relu), vectorized float4 store over the pixel quad
#pragma unroll
    for (int q = 0; q < 2; q++) {
        int Y = y + 8 * q;
#pragma unroll
        for (int j = 0; j < 8; j++) {
            int co = tc * 64 + co0 + j;
            float bv = bias[co];
            float4 v;
            v.x = acc[q][j][0] + bv;
            v.y = acc[q][j][1] + bv;
            v.z = acc[q][j][2] + bv;
            v.w = acc[q][j][3] + bv;
            if (RELU) {
                v.x = fmaxf(v.x, 0.f); v.y = fmaxf(v.y, 0.f);
                v.z = fmaxf(v.z, 0.f); v.w = fmaxf(v.w, 0.f);
            }
            *(float4*)&out[((size_t)b * COUT + co) * 256 + Y * 16 + x0] = v;
        }
    }
}

// Per-batch: qy_logits (dot over 32768), gamma/beta, gumbel-softmax y, JS, CE.
__global__ __launch_bounds__(256)
void logits_kernel(const float* __restrict__ h, const float* __restrict__ lin_w,
                   const float* __restrict__ lin_b,
                   const float* __restrict__ gamma_w, const float* __restrict__ gamma_b,
                   const float* __restrict__ beta_w, const float* __restrict__ beta_b,
                   const float* __restrict__ u_g, const int* __restrict__ label,
                   float* __restrict__ gamma_ws, float* __restrict__ beta_ws,
                   float* out) {
    int b = blockIdx.x, tid = threadIdx.x;
    const float* hb = h + (size_t)b * 32768;
    float a0 = 0.f, a1 = 0.f, a2 = 0.f, a3 = 0.f;
    for (int i = tid; i < 32768; i += 256) {
        float hv = hb[i];
        a0 = fmaf(hv, lin_w[i], a0);
        a1 = fmaf(hv, lin_w[i + 32768], a1);
        a2 = fmaf(hv, lin_w[i + 65536], a2);
        a3 = fmaf(hv, lin_w[i + 98304], a3);
    }
    __shared__ float red[4][256];
    red[0][tid] = a0; red[1][tid] = a1; red[2][tid] = a2; red[3][tid] = a3;
    __syncthreads();
    for (int st = 128; st > 0; st >>= 1) {
        if (tid < st) {
            red[0][tid] += red[0][tid + st];
            red[1][tid] += red[1][tid + st];
            red[2][tid] += red[2][tid + st];
            red[3][tid] += red[3][tid + st];
        }
        __syncthreads();
    }
    float l0 = red[0][0] + lin_b[0];
    float l1 = red[1][0] + lin_b[1];
    float l2 = red[2][0] + lin_b[2];
    float l3 = red[3][0] + lin_b[3];

    {   // gamma/beta for channel c = tid
        const float* gw = gamma_w + tid * 4;
        const float* bw = beta_w + tid * 4;
        float g  = fmaf(l0, gw[0], fmaf(l1, gw[1], fmaf(l2, gw[2], fmaf(l3, gw[3], gamma_b[tid]))));
        float be = fmaf(l0, bw[0], fmaf(l1, bw[1], fmaf(l2, bw[2], fmaf(l3, bw[3], beta_b[tid]))));
        gamma_ws[b * 256 + tid] = g;
        beta_ws[b * 256 + tid]  = be;
    }

    if (tid == 0) {
        float l[4] = {l0, l1, l2, l3};
        float t[4], y[4];
        float mx = -1e30f;
        for (int k = 0; k < 4; k++) {
            float u = u_g[b * 4 + k];
            float g = -logf(-logf(u));
            t[k] = l[k] + g;   // TAU = 1
            mx = fmaxf(mx, t[k]);
        }
        float sum = 0.f;
        for (int k = 0; k < 4; k++) { y[k] = expf(t[k] - mx); sum += y[k]; }
        float inv = 1.f / sum;
        float js1 = 0.f, js2 = 0.f;
        for (int k = 0; k < 4; k++) {
            y[k] *= inv;
            out[OFF_Y + b * 4 + k] = y[k];
            float m = 0.5f * (y[k] + 0.25f) + 1e-10f;
            js1 += y[k] * logf(y[k] / m);
            js2 += 0.25f * logf(0.25f / m);
        }
        float js = 0.5f * js1 + 0.5f * js2;
        atomicAdd(&out[OFF_KL], js * (1.f / 256.f));

        float mx2 = fmaxf(fmaxf(l0, l1), fmaxf(l2, l3));
        float s2 = expf(l0 - mx2) + expf(l1 - mx2) + expf(l2 - mx2) + expf(l3 - mx2);
        float lse = mx2 + logf(s2);
        int lab = label[b];
        float ce = lse - l[lab];
        atomicAdd(&out[OFF_CE], ce * (1.f / 256.f));
    }
}

// clamp qz -> (q_mu, q_lv, q_std); z = q_mu + q_std*eps; logprob_q.
__global__ __launch_bounds__(256)
void clamp_z_kernel(const float* __restrict__ qz, const float* __restrict__ eps,
                    float* __restrict__ out, float* __restrict__ qstd_ws) {
    int idx = blockIdx.x * 256 + threadIdx.x;   // 8,388,608 total
    int b = idx >> 15;
    int rem = idx & 32767;
    const float* qb = qz + (size_t)b * 65536;
    float mu = qb[rem];
    float lv = qb[rem + 32768];
    mu = fminf(fmaxf(mu, -10.f), 10.f);
    lv = fminf(fmaxf(lv, -10.f), 10.f);
    float sd = lv < 0.f ? expf(0.5f * lv) : 1.f + lv;
    float e = eps[idx];
    float z = fmaf(sd, e, mu);
    float d = (z - mu) / sd;
    float lq = fmaf(-0.5f, d * d, -logf(sd) - LOG2PI_HALF);
    out[OFF_QMU + (size_t)idx] = mu;
    out[OFF_QLV + (size_t)idx] = lv;
    out[OFF_Z   + (size_t)idx] = z;
    out[OFF_LQ  + (size_t)idx] = lq;
    qstd_ws[idx] = sd;
}

// logprob_p (all K, vectorized float4 store) + labeled-component KL reduction.
__global__ __launch_bounds__(256)
void logp_kl_kernel(const float* __restrict__ p, const float* __restrict__ qstd_ws,
                    const int* __restrict__ label, float* out) {
    int idx = blockIdx.x * 256 + threadIdx.x;   // 8,388,608 total
    int b = idx >> 15;
    int rem = idx & 32767;
    int c = rem >> 8;
    int hw = rem & 255;
    float zv = out[OFF_Z + (size_t)idx];
    float qm = out[OFF_QMU + (size_t)idx];
    float qs = qstd_ws[idx];
    float logqs = __logf(qs);
    float qs2 = qs * qs;
    int lab = label[b];
    const float* pb = p + (size_t)b * 262144;
    float klv = 0.f;
    float lpv[4];
#pragma unroll
    for (int k = 0; k < 4; k++) {
        float pm = pb[(k * 128 + c) * 256 + hw];
        float pl = pb[(512 + k * 128 + c) * 256 + hw];
        pm = fminf(fmaxf(pm, -10.f), 10.f);
        pl = fminf(fmaxf(pl, -10.f), 10.f);
        float ps = pl < 0.f ? __expf(0.5f * pl) : 1.f + pl;
        float logps = __logf(ps);
        float dd = (zv - pm) / ps;
        lpv[k] = fmaf(-0.5f, dd * dd, -logps - LOG2PI_HALF);
        if (k == lab) {
            float dm = qm - pm;
            klv = logps - logqs + (qs2 + dm * dm) / (2.f * ps * ps) - 0.5f;
        }
    }
    float4 lp; lp.x = lpv[0]; lp.y = lpv[1]; lp.z = lpv[2]; lp.w = lpv[3];
    *(float4*)&out[OFF_LP + (size_t)idx * 4] = lp;

    __shared__ float red[256];
    red[threadIdx.x] = klv;
    __syncthreads();
    for (int st = 128; st > 0; st >>= 1) {
        if (threadIdx.x < st) red[threadIdx.x] += red[threadIdx.x + st];
        __syncthreads();
    }
    if (threadIdx.x == 0)
        atomicAdd(&out[OFF_KL], red[0] * (1.f / 8388608.f));
}

extern "C" void kernel_launch(void* const* d_in, const int* in_sizes, int n_in,
                              void* d_out_v, int out_size, void* d_ws, size_t ws_size,
                              hipStream_t stream) {
    const float* p_params  = (const float*)d_in[0];
    const float* q_params  = (const float*)d_in[1];
    const int*   label     = (const int*)d_in[2];
    const float* eps       = (const float*)d_in[3];
    const float* u_gum     = (const float*)d_in[4];
    const float* qy_conv_w = (const float*)d_in[5];
    const float* qy_conv_b = (const float*)d_in[6];
    const float* qy_lin_w  = (const float*)d_in[7];
    const float* qy_lin_b  = (const float*)d_in[8];
    const float* gamma_w   = (const float*)d_in[9];
    const float* gamma_b   = (const float*)d_in[10];
    const float* beta_w    = (const float*)d_in[11];
    const float* beta_b    = (const float*)d_in[12];
    const float* qz1_w     = (const float*)d_in[13];
    const float* qz1_b     = (const float*)d_in[14];
    const float* qz2_w     = (const float*)d_in[15];
    const float* qz2_b     = (const float*)d_in[16];
    const float* out_w     = (const float*)d_in[17];
    const float* out_b     = (const float*)d_in[18];
    float* out = (float*)d_out_v;
    float* ws  = (float*)d_ws;

    // workspace layout (floats)
    float* w1t   = ws;                   // 294912
    float* w2t   = w1t + 294912;         // 589824
    float* w3t   = w2t + 589824;         // 589824
    float* w4t   = w3t + 589824;         // 294912
    float* gamma = w4t + 294912;         // 65536
    float* beta  = gamma + 65536;        // 65536
    float* h     = beta + 65536;         // 8388608
    float* t1    = h + 8388608;          // 16777216
    float* qz    = t1 + 16777216;        // 16777216
    float* qstd  = qz + 16777216;        // 8388608
    // total: 52,232,192 floats ~= 209 MB

    zero_scalars<<<1, 64, 0, stream>>>(out);

    wtrans_kernel<<<(294912 + 255) / 256, 256, 0, stream>>>(qy_conv_w, w1t, 256, 128);
    wtrans_kernel<<<(589824 + 255) / 256, 256, 0, stream>>>(qz1_w, w2t, 256, 256);
    wtrans_kernel<<<(589824 + 255) / 256, 256, 0, stream>>>(qz2_w, w3t, 256, 256);
    wtrans_kernel<<<(294912 + 255) / 256, 256, 0, stream>>>(out_w, w4t, 128, 256);

    // h = relu(conv(q_params, qy_conv_w) + b)
    conv3x3_kernel<256, 128, true, false><<<256 * 2, 256, 0, stream>>>(
        q_params, w1t, qy_conv_b, nullptr, nullptr, h);

    // qy_logits, gamma/beta, y, JS, CE
    logits_kernel<<<256, 256, 0, stream>>>(h, qy_lin_w, qy_lin_b, gamma_w, gamma_b,
                                           beta_w, beta_b, u_gum, label, gamma, beta, out);

    // t1 = relu(conv(gamma*q+beta, qz1_w) + b)   (affine fused into staging)
    conv3x3_kernel<256, 256, true, true><<<256 * 4, 256, 0, stream>>>(
        q_params, w2t, qz1_b, gamma, beta, t1);

    // qz = conv(t1, qz2_w) + b
    conv3x3_kernel<256, 256, false, false><<<256 * 4, 256, 0, stream>>>(
        t1, w3t, qz2_b, nullptr, nullptr, qz);

    // clamp, z, logprob_q, q_mu/q_lv outputs
    clamp_z_kernel<<<32768, 256, 0, stream>>>(qz, eps, out, qstd);

    // out = conv(z, out_w) + b
    conv3x3_kernel<128, 256, false, false><<<256 * 4, 256, 0, stream>>>(
        out + OFF_Z, w4t, out_b, nullptr, nullptr, out + OFF_OUT);

    // logprob_p + KL(labeled component)
    logp_kl_kernel<<<32768, 256, 0, stream>>>(p_params, qstd, label, out);
}

// Round 2
// 1825.375 us; speedup vs baseline: 2.4512x; 2.4512x over previous
//
#include <hip/hip_runtime.h>
#include <cstdint>
#include <cstddef>

// ---------------------------------------------------------------------------
// MixtureStochasticConvBlock — fp16-MFMA convs + fp32 elementwise tail.
// B=256, C_IN=256, C_V=128, C_OUT=256, H=W=16, K=4, TAU=1.
// Conv = implicit GEMM, A-operand = pixels, B-operand = weights:
//   D[x][co] += sum_ci A[x][ci] * B[ci][co]  per (row y, kh, kw)
// so D rows (quad*4+reg) are 4 consecutive x -> coalesced c-major stores.
// ---------------------------------------------------------------------------

#define LOG2PI_HALF 0.91893853320467274f

typedef _Float16 half8 __attribute__((ext_vector_type(8)));
typedef float f32x4 __attribute__((ext_vector_type(4)));

static constexpr size_t OFF_OUT = 0;
static constexpr size_t OFF_Z   = 16777216;
static constexpr size_t OFF_LP  = 25165824;
static constexpr size_t OFF_LQ  = 58720256;
static constexpr size_t OFF_KL  = 67108864;
static constexpr size_t OFF_QMU = 67108865;
static constexpr size_t OFF_QLV = 75497473;
static constexpr size_t OFF_Y   = 83886081;
static constexpr size_t OFF_CE  = 83887105;

__global__ void zero_scalars(float* __restrict__ out) {
    if (threadIdx.x == 0) {
        out[OFF_KL] = 0.f;
        out[OFF_CE] = 0.f;
    }
}

// OIHW fp32 -> wb[(((kap*NCC + cc)*COUT + co)*4 + q)*8 + s] fp16,
// ci = cc*32 + q*8 + s.  (B-fragment-contiguous layout.)
__global__ void wrepack(const float* __restrict__ w, _Float16* __restrict__ wb,
                        int CIN, int COUT) {
    int idx = blockIdx.x * 256 + threadIdx.x;
    int total = 9 * CIN * COUT;
    if (idx >= total) return;
    int s = idx & 7;
    int t = idx >> 3;
    int q = t & 3; t >>= 2;
    int co = t % COUT; t /= COUT;
    int ncc = CIN / 32;
    int cc = t % ncc;
    int kap = t / ncc;
    int ci = cc * 32 + q * 8 + s;
    wb[idx] = (_Float16)w[((size_t)co * CIN + ci) * 9 + kap];
}

// fp32 c-major [b][CIN][256] -> fp16 pixel-major [b][256][CIN], LDS-tiled.
template <int CIN>
__global__ __launch_bounds__(256)
void transpose_pixmajor(const float* __restrict__ src, _Float16* __restrict__ dst) {
    const int ntc = CIN / 64;
    int bt = blockIdx.x;
    int b = bt / (ntc * 4);
    int rem = bt % (ntc * 4);
    int tci = rem >> 2;
    int tpx = rem & 3;
    __shared__ float s[64][65];
    int tid = threadIdx.x;
    int r0 = tid >> 4;
    int c4 = (tid & 15) * 4;
#pragma unroll
    for (int i = 0; i < 4; i++) {
        int ci_l = i * 16 + r0;
        const float* sp = src + ((size_t)b * CIN + tci * 64 + ci_l) * 256 + tpx * 64 + c4;
        float4 v = *(const float4*)sp;
        s[ci_l][c4] = v.x; s[ci_l][c4 + 1] = v.y;
        s[ci_l][c4 + 2] = v.z; s[ci_l][c4 + 3] = v.w;
    }
    __syncthreads();
#pragma unroll
    for (int j = 0; j < 2; j++) {
        int idx = j * 256 + tid;
        int px_l = idx >> 3, c8 = idx & 7;
        half8 v;
#pragma unroll
        for (int s2 = 0; s2 < 8; s2++) v[s2] = (_Float16)s[c8 * 8 + s2][px_l];
        *(half8*)&dst[((size_t)b * 256 + tpx * 64 + px_l) * CIN + tci * 64 + c8 * 8] = v;
    }
}

// 3x3 SAME conv via MFMA. Workgroup: 1 batch x 64 couts x 256 pixels, 4 waves
// (wave w = rows 4w..4w+3). LDS: input chunk (32 ci, haloed, fragment layout)
// + double-buffered weights.  OUT_F16PM: write fp16 pixel-major via wave-LDS
// transpose (for next conv's staging); else fp32 c-major direct.
template <int CIN, int COUT, bool RELU, bool FUSE_GB, bool OUT_F16PM>
__global__ __launch_bounds__(256, 2)
void conv_mfma(const _Float16* __restrict__ xT,   // [B][256][CIN] fp16 pixel-major
               const _Float16* __restrict__ wb,   // repacked weights
               const float* __restrict__ bias,
               const float* __restrict__ gamma, const float* __restrict__ beta,
               void* __restrict__ outp) {
    constexpr int NCC = CIN / 32;
    __shared__ __align__(16) _Float16 s_x[4 * 18 * 18 * 8];  // 20736 B
    __shared__ __align__(16) _Float16 s_w[2 * 64 * 40];      // padded stride 40

    const int nco = COUT / 64;
    const int b  = blockIdx.x / nco;
    const int cb = blockIdx.x % nco;
    const int tid  = threadIdx.x;
    const int wv   = tid >> 6;
    const int lane = tid & 63;
    const int n16  = lane & 15;
    const int q4   = lane >> 4;

    f32x4 acc[4][4];
#pragma unroll
    for (int t = 0; t < 4; t++)
#pragma unroll
        for (int n = 0; n < 4; n++) acc[t][n] = (f32x4){0.f, 0.f, 0.f, 0.f};

    const _Float16* xTb = xT + (size_t)b * 256 * CIN;
    const int co_st = tid >> 2, q_st = tid & 3;   // weight-staging roles

    for (int cc = 0; cc < NCC; cc++) {
        // stage input chunk (halo zero-padded) into s_x[q][yy][xx][8]
        for (int it = 0; it < 6; ++it) {
            int idx = it * 256 + tid;
            if (idx < 1296) {
                int pix = idx >> 2;
                int q = idx & 3;
                int yy = pix / 18;
                int xx = pix - yy * 18;
                half8 v;
#pragma unroll
                for (int s2 = 0; s2 < 8; ++s2) v[s2] = (_Float16)0.f;
                if (yy >= 1 && yy <= 16 && xx >= 1 && xx <= 16) {
                    const _Float16* src =
                        xTb + ((size_t)((yy - 1) * 16 + (xx - 1))) * CIN + cc * 32 + q * 8;
                    v = *(const half8*)src;
                    if (FUSE_GB) {
                        const float* gp = gamma + b * CIN + cc * 32 + q * 8;
                        const float* bp = beta  + b * CIN + cc * 32 + q * 8;
#pragma unroll
                        for (int s2 = 0; s2 < 8; ++s2)
                            v[s2] = (_Float16)fmaf(gp[s2], (float)v[s2], bp[s2]);
                    }
                }
                *(half8*)&s_x[((q * 18 + yy) * 18 + xx) * 8] = v;
            }
        }
        // stage weights for kap=0 into buffer 0
        {
            const _Float16* src =
                wb + ((((size_t)0 * NCC + cc) * COUT + cb * 64 + co_st) * 4 + q_st) * 8;
            *(half8*)&s_w[co_st * 40 + q_st * 8] = *(const half8*)src;
        }
        __syncthreads();

        for (int kap = 0; kap < 9; ++kap) {
            const int pb = (kap & 1) * 2560;
            half8 wnext;
            if (kap < 8) {
                const _Float16* src =
                    wb + ((((size_t)(kap + 1) * NCC + cc) * COUT + cb * 64 + co_st) * 4 + q_st) * 8;
                wnext = *(const half8*)src;
            }
            const int kh = kap / 3;
            const int kw = kap - kh * 3;

            half8 af[4], bf[4];
#pragma unroll
            for (int t = 0; t < 4; t++) {
                int y = wv * 4 + t;
                af[t] = *(const half8*)&s_x[((q4 * 18 + (y + kh)) * 18 + (n16 + kw)) * 8];
            }
#pragma unroll
            for (int nt = 0; nt < 4; nt++)
                bf[nt] = *(const half8*)&s_w[pb + (nt * 16 + n16) * 40 + q4 * 8];
#pragma unroll
            for (int t = 0; t < 4; t++)
#pragma unroll
                for (int nt = 0; nt < 4; nt++)
                    acc[t][nt] = __builtin_amdgcn_mfma_f32_16x16x32_f16(
                        af[t], bf[nt], acc[t][nt], 0, 0, 0);

            if (kap < 8)
                *(half8*)&s_w[(2560 - pb) + co_st * 40 + q_st * 8] = wnext;
            __syncthreads();
        }
    }

    if (!OUT_F16PM) {
        // fp32 c-major: lane holds 4 consecutive x at fixed co -> float4 store
        float* out = (float*)outp;
#pragma unroll
        for (int t = 0; t < 4; t++) {
            int y = wv * 4 + t;
#pragma unroll
            for (int nt = 0; nt < 4; nt++) {
                int co = cb * 64 + nt * 16 + n16;
                float bv = bias[co];
                float4 v;
                v.x = acc[t][nt][0] + bv;
                v.y = acc[t][nt][1] + bv;
                v.z = acc[t][nt][2] + bv;
                v.w = acc[t][nt][3] + bv;
                if (RELU) {
                    v.x = fmaxf(v.x, 0.f); v.y = fmaxf(v.y, 0.f);
                    v.z = fmaxf(v.z, 0.f); v.w = fmaxf(v.w, 0.f);
                }
                *(float4*)&out[((size_t)b * COUT + co) * 256 + y * 16 + q4 * 4] = v;
            }
        }
    } else {
        // fp16 pixel-major via per-wave LDS transpose (reuse s_x, stride 72)
        _Float16* t1 = (_Float16*)outp;
        _Float16* slice = &s_x[wv * 16 * 72];
#pragma unroll 1
        for (int t = 0; t < 4; t++) {
            __syncthreads();
#pragma unroll
            for (int nt = 0; nt < 4; nt++) {
                int co = cb * 64 + nt * 16 + n16;
                float bv = bias[co];
#pragma unroll
                for (int r = 0; r < 4; r++) {
                    float v = acc[t][nt][r] + bv;
                    if (RELU) v = fmaxf(v, 0.f);
                    slice[(q4 * 4 + r) * 72 + nt * 16 + n16] = (_Float16)v;
                }
            }
            __syncthreads();
            int y = wv * 4 + t;
#pragma unroll
            for (int hh = 0; hh < 2; hh++) {
                int idx = hh * 64 + lane;
                int x = idx >> 3, c8 = idx & 7;
                half8 v = *(half8*)&slice[x * 72 + c8 * 8];
                *(half8*)&t1[((size_t)b * 256 + y * 16 + x) * COUT + cb * 64 + c8 * 8] = v;
            }
        }
    }
}

// Per-batch: qy_logits (dot over 32768), gamma/beta, gumbel-softmax y, JS, CE.
__global__ __launch_bounds__(256)
void logits_kernel(const float* __restrict__ h, const float* __restrict__ lin_w,
                   const float* __restrict__ lin_b,
                   const float* __restrict__ gamma_w, const float* __restrict__ gamma_b,
                   const float* __restrict__ beta_w, const float* __restrict__ beta_b,
                   const float* __restrict__ u_g, const int* __restrict__ label,
                   float* __restrict__ gamma_ws, float* __restrict__ beta_ws,
                   float* out) {
    int b = blockIdx.x, tid = threadIdx.x;
    const float* hb = h + (size_t)b * 32768;
    float a0 = 0.f, a1 = 0.f, a2 = 0.f, a3 = 0.f;
    for (int i = tid; i < 32768; i += 256) {
        float hv = hb[i];
        a0 = fmaf(hv, lin_w[i], a0);
        a1 = fmaf(hv, lin_w[i + 32768], a1);
        a2 = fmaf(hv, lin_w[i + 65536], a2);
        a3 = fmaf(hv, lin_w[i + 98304], a3);
    }
    __shared__ float red[4][256];
    red[0][tid] = a0; red[1][tid] = a1; red[2][tid] = a2; red[3][tid] = a3;
    __syncthreads();
    for (int st = 128; st > 0; st >>= 1) {
        if (tid < st) {
            red[0][tid] += red[0][tid + st];
            red[1][tid] += red[1][tid + st];
            red[2][tid] += red[2][tid + st];
            red[3][tid] += red[3][tid + st];
        }
        __syncthreads();
    }
    float l0 = red[0][0] + lin_b[0];
    float l1 = red[1][0] + lin_b[1];
    float l2 = red[2][0] + lin_b[2];
    float l3 = red[3][0] + lin_b[3];

    {
        const float* gw = gamma_w + tid * 4;
        const float* bw = beta_w + tid * 4;
        float g  = fmaf(l0, gw[0], fmaf(l1, gw[1], fmaf(l2, gw[2], fmaf(l3, gw[3], gamma_b[tid]))));
        float be = fmaf(l0, bw[0], fmaf(l1, bw[1], fmaf(l2, bw[2], fmaf(l3, bw[3], beta_b[tid]))));
        gamma_ws[b * 256 + tid] = g;
        beta_ws[b * 256 + tid]  = be;
    }

    if (tid == 0) {
        float l[4] = {l0, l1, l2, l3};
        float t[4], y[4];
        float mx = -1e30f;
        for (int k = 0; k < 4; k++) {
            float u = u_g[b * 4 + k];
            float g = -logf(-logf(u));
            t[k] = l[k] + g;
            mx = fmaxf(mx, t[k]);
        }
        float sum = 0.f;
        for (int k = 0; k < 4; k++) { y[k] = expf(t[k] - mx); sum += y[k]; }
        float inv = 1.f / sum;
        float js1 = 0.f, js2 = 0.f;
        for (int k = 0; k < 4; k++) {
            y[k] *= inv;
            out[OFF_Y + b * 4 + k] = y[k];
            float m = 0.5f * (y[k] + 0.25f) + 1e-10f;
            js1 += y[k] * logf(y[k] / m);
            js2 += 0.25f * logf(0.25f / m);
        }
        float js = 0.5f * js1 + 0.5f * js2;
        atomicAdd(&out[OFF_KL], js * (1.f / 256.f));

        float mx2 = fmaxf(fmaxf(l0, l1), fmaxf(l2, l3));
        float s2 = expf(l0 - mx2) + expf(l1 - mx2) + expf(l2 - mx2) + expf(l3 - mx2);
        float lse = mx2 + logf(s2);
        int lab = label[b];
        float ce = lse - l[lab];
        atomicAdd(&out[OFF_CE], ce * (1.f / 256.f));
    }
}

// clamp qz -> (q_mu, q_lv); z = q_mu + q_std*eps; logprob_q.
__global__ __launch_bounds__(256)
void clamp_z_kernel(const float* __restrict__ qz, const float* __restrict__ eps,
                    float* __restrict__ out) {
    int idx = blockIdx.x * 256 + threadIdx.x;
    int b = idx >> 15;
    int rem = idx & 32767;
    const float* qb = qz + (size_t)b * 65536;
    float mu = qb[rem];
    float lv = qb[rem + 32768];
    mu = fminf(fmaxf(mu, -10.f), 10.f);
    lv = fminf(fmaxf(lv, -10.f), 10.f);
    float sd = lv < 0.f ? expf(0.5f * lv) : 1.f + lv;
    float e = eps[idx];
    float z = fmaf(sd, e, mu);
    float d = (z - mu) / sd;
    float lq = fmaf(-0.5f, d * d, -logf(sd) - LOG2PI_HALF);
    out[OFF_QMU + (size_t)idx] = mu;
    out[OFF_QLV + (size_t)idx] = lv;
    out[OFF_Z   + (size_t)idx] = z;
    out[OFF_LQ  + (size_t)idx] = lq;
}

// logprob_p (all K) + labeled-component KL reduction. q_std recomputed from lv.
__global__ __launch_bounds__(256)
void logp_kl_kernel(const float* __restrict__ p, const int* __restrict__ label,
                    float* out) {
    int idx = blockIdx.x * 256 + threadIdx.x;
    int b = idx >> 15;
    int rem = idx & 32767;
    int c = rem >> 8;
    int hw = rem & 255;
    float zv = out[OFF_Z + (size_t)idx];
    float qm = out[OFF_QMU + (size_t)idx];
    float lv = out[OFF_QLV + (size_t)idx];
    float qs = lv < 0.f ? __expf(0.5f * lv) : 1.f + lv;
    float logqs = __logf(qs);
    float qs2 = qs * qs;
    int lab = label[b];
    const float* pb = p + (size_t)b * 262144;
    float klv = 0.f;
    float lpv[4];
#pragma unroll
    for (int k = 0; k < 4; k++) {
        float pm = pb[(k * 128 + c) * 256 + hw];
        float pl = pb[(512 + k * 128 + c) * 256 + hw];
        pm = fminf(fmaxf(pm, -10.f), 10.f);
        pl = fminf(fmaxf(pl, -10.f), 10.f);
        float ps = pl < 0.f ? __expf(0.5f * pl) : 1.f + pl;
        float logps = __logf(ps);
        float dd = (zv - pm) / ps;
        lpv[k] = fmaf(-0.5f, dd * dd, -logps - LOG2PI_HALF);
        if (k == lab) {
            float dm = qm - pm;
            klv = logps - logqs + (qs2 + dm * dm) / (2.f * ps * ps) - 0.5f;
        }
    }
    float4 lp; lp.x = lpv[0]; lp.y = lpv[1]; lp.z = lpv[2]; lp.w = lpv[3];
    *(float4*)&out[OFF_LP + (size_t)idx * 4] = lp;

    __shared__ float red[256];
    red[threadIdx.x] = klv;
    __syncthreads();
    for (int st = 128; st > 0; st >>= 1) {
        if (threadIdx.x < st) red[threadIdx.x] += red[threadIdx.x + st];
        __syncthreads();
    }
    if (threadIdx.x == 0)
        atomicAdd(&out[OFF_KL], red[0] * (1.f / 8388608.f));
}

extern "C" void kernel_launch(void* const* d_in, const int* in_sizes, int n_in,
                              void* d_out_v, int out_size, void* d_ws, size_t ws_size,
                              hipStream_t stream) {
    const float* p_params  = (const float*)d_in[0];
    const float* q_params  = (const float*)d_in[1];
    const int*   label     = (const int*)d_in[2];
    const float* eps       = (const float*)d_in[3];
    const float* u_gum     = (const float*)d_in[4];
    const float* qy_conv_w = (const float*)d_in[5];
    const float* qy_conv_b = (const float*)d_in[6];
    const float* qy_lin_w  = (const float*)d_in[7];
    const float* qy_lin_b  = (const float*)d_in[8];
    const float* gamma_w   = (const float*)d_in[9];
    const float* gamma_b   = (const float*)d_in[10];
    const float* beta_w    = (const float*)d_in[11];
    const float* beta_b    = (const float*)d_in[12];
    const float* qz1_w     = (const float*)d_in[13];
    const float* qz1_b     = (const float*)d_in[14];
    const float* qz2_w     = (const float*)d_in[15];
    const float* qz2_b     = (const float*)d_in[16];
    const float* out_w     = (const float*)d_in[17];
    const float* out_b     = (const float*)d_in[18];
    float* out = (float*)d_out_v;

    // workspace: fp16 region then fp32 region
    _Float16* hws = (_Float16*)d_ws;
    _Float16* wb1 = hws;                    //   294912 fp16
    _Float16* wb2 = wb1 + 294912;           //   589824
    _Float16* wb3 = wb2 + 589824;           //   589824
    _Float16* wb4 = wb3 + 589824;           //   294912
    _Float16* qT  = wb4 + 294912;           // 16777216  [B][256][256]
    _Float16* zT  = qT + 16777216;          //  8388608  [B][256][128]
    _Float16* t1  = zT + 8388608;           // 16777216  [B][256][256]
    float* fws   = (float*)(t1 + 16777216);
    float* gamma = fws;                     //    65536
    float* beta  = gamma + 65536;           //    65536
    float* h     = beta + 65536;            //  8388608  [B][128][256] fp32
    float* qz    = h + 8388608;             // 16777216  [B][256][256] fp32
    // total ~189 MB

    zero_scalars<<<1, 64, 0, stream>>>(out);

    wrepack<<<1152, 256, 0, stream>>>(qy_conv_w, wb1, 256, 128);
    wrepack<<<2304, 256, 0, stream>>>(qz1_w, wb2, 256, 256);
    wrepack<<<2304, 256, 0, stream>>>(qz2_w, wb3, 256, 256);
    wrepack<<<1152, 256, 0, stream>>>(out_w, wb4, 128, 256);

    // q_params -> fp16 pixel-major
    transpose_pixmajor<256><<<4096, 256, 0, stream>>>(q_params, qT);

    // h = relu(conv(q_params)) -> fp32 c-major
    conv_mfma<256, 128, true, false, false><<<512, 256, 0, stream>>>(
        qT, wb1, qy_conv_b, nullptr, nullptr, h);

    logits_kernel<<<256, 256, 0, stream>>>(h, qy_lin_w, qy_lin_b, gamma_w, gamma_b,
                                           beta_w, beta_b, u_gum, label, gamma, beta, out);

    // t1 = relu(conv(gamma*q+beta)) -> fp16 pixel-major (affine fused in staging)
    conv_mfma<256, 256, true, true, true><<<1024, 256, 0, stream>>>(
        qT, wb2, qz1_b, gamma, beta, t1);

    // qz = conv(t1) -> fp32 c-major
    conv_mfma<256, 256, false, false, false><<<1024, 256, 0, stream>>>(
        t1, wb3, qz2_b, nullptr, nullptr, qz);

    clamp_z_kernel<<<32768, 256, 0, stream>>>(qz, eps, out);

    // z -> fp16 pixel-major
    transpose_pixmajor<128><<<2048, 256, 0, stream>>>(out + OFF_Z, zT);

    // out = conv(z) -> fp32 c-major
    conv_mfma<128, 256, false, false, false><<<1024, 256, 0, stream>>>(
        zT, wb4, out_b, nullptr, nullptr, out + OFF_OUT);

    logp_kl_kernel<<<32768, 256, 0, stream>>>(p_params, label, out);
}